// Round 11
// baseline (145.351 us; speedup 1.0000x reference)
//
#include <hip/hip_runtime.h>

#define BB 8
#define CC 64
#define HH 256
#define WW 256
#define KK 5

// Shared conv core on a 68x76 LDS tile: 4x4 outputs/thread, thread (tid>>4,
// tid&15) covers a 64x64 tile; reads 8 rows x 3 aligned float4, e[j+kx+2].
__device__ __forceinline__ void conv_core(const float* __restrict__ sx,
                                          const float* __restrict__ w,
                                          float bv, int tid, float acc[4][4])
{
    const int tr = (tid >> 4) * 4;
    const int tc = (tid & 15) * 4;
#pragma unroll
    for (int i = 0; i < 4; i++)
#pragma unroll
        for (int j = 0; j < 4; j++) acc[i][j] = bv;
#pragma unroll
    for (int ir = 0; ir < 8; ir++) {
        const float* s = &sx[(tr + ir) * 76 + tc];
        float4 A = *(const float4*)s;
        float4 B4 = *(const float4*)(s + 4);
        float4 Cv = *(const float4*)(s + 8);
        float e[12] = {A.x, A.y, A.z, A.w, B4.x, B4.y, B4.z, B4.w,
                       Cv.x, Cv.y, Cv.z, Cv.w};
#pragma unroll
        for (int i = 0; i < 4; i++) {
            const int ky = ir - i;
            if (ky >= 0 && ky < 5) {
#pragma unroll
                for (int kx = 0; kx < 5; kx++) {
                    const float wv = w[ky * 5 + kx];
#pragma unroll
                    for (int j = 0; j < 4; j++) acc[i][j] += e[j + kx + 2] * wv;
                }
            }
        }
    }
}

// ---------------------------------------------------------------------------
// k_c1: avgpool(2x2 of x) fused into fill + dwconv1 -> p1 (128^2/plane).
// Grid (2,2,512), 256 thr, LDS 68x76, ONE barrier.
// Buffer row r = pooled row R0-2+r; dword 4q = pooled col C0-4+4q.
// ---------------------------------------------------------------------------
__global__ __launch_bounds__(256, 8) void k_c1(
    const float* __restrict__ x, const float* __restrict__ w1,
    const float* __restrict__ b1, float* __restrict__ p1)
{
    const int plane = blockIdx.z;
    const int c = plane & 63;
    const int C0 = blockIdx.x * 64, R0 = blockIdx.y * 64;
    const int tid = threadIdx.x;

    __shared__ __align__(16) float sx[68 * 76];
    const float* xp = x + (size_t)plane * HH * WW;

#pragma unroll
    for (int k = 0; k < 5; k++) {
        int i = tid + k * 256;
        if (i < 68 * 18) {
            int r = i / 18, q = i - r * 18;
            int pr = R0 - 2 + r;
            bool cok = (q >= 1 && q <= 16) || (q == 0 && C0 == 64) || (q == 17 && C0 == 0);
            float4 v = make_float4(0.f, 0.f, 0.f, 0.f);
            if ((unsigned)pr < 128u && cok) {
                int xc = 2 * C0 - 8 + 8 * q;           // aligned
                const float* p0 = xp + (size_t)(2 * pr) * WW + xc;
                float4 a0 = *(const float4*)p0;
                float4 a1 = *(const float4*)(p0 + 4);
                float4 b0 = *(const float4*)(p0 + WW);
                float4 b1v = *(const float4*)(p0 + WW + 4);
                v.x = 0.25f * (a0.x + a0.y + b0.x + b0.y);
                v.y = 0.25f * (a0.z + a0.w + b0.z + b0.w);
                v.z = 0.25f * (a1.x + a1.y + b1v.x + b1v.y);
                v.w = 0.25f * (a1.z + a1.w + b1v.z + b1v.w);
            }
            *(float4*)&sx[r * 76 + 4 * q] = v;
        }
    }

    float w[25];
#pragma unroll
    for (int k = 0; k < 25; k++) w[k] = w1[c * 25 + k];       // uniform
    const float bv = b1[c];
    __syncthreads();

    float acc[4][4];
    conv_core(sx, w, bv, tid, acc);

    const int tr = (tid >> 4) * 4, tc = (tid & 15) * 4;
    float* op = p1 + (size_t)plane * 16384 + (size_t)(R0 + tr) * 128 + C0 + tc;
#pragma unroll
    for (int i = 0; i < 4; i++)
        *(float4*)(op + (size_t)i * 128) = make_float4(acc[i][0], acc[i][1], acc[i][2], acc[i][3]);
}

// ---------------------------------------------------------------------------
// k_c2: dwconv2 on p1 (128^2) -> p2. Same shape as k_c1, plain fill.
// ---------------------------------------------------------------------------
__global__ __launch_bounds__(256, 8) void k_c2(
    const float* __restrict__ p1, const float* __restrict__ w1,
    const float* __restrict__ b1, float* __restrict__ p2)
{
    const int plane = blockIdx.z;
    const int c = plane & 63;
    const int C0 = blockIdx.x * 64, R0 = blockIdx.y * 64;
    const int tid = threadIdx.x;

    __shared__ __align__(16) float sx[68 * 76];
    const float* pp = p1 + (size_t)plane * 16384;

#pragma unroll
    for (int k = 0; k < 5; k++) {
        int i = tid + k * 256;
        if (i < 68 * 18) {
            int r = i / 18, q = i - r * 18;
            int gr = R0 - 2 + r;
            bool cok = (q >= 1 && q <= 16) || (q == 0 && C0 == 64) || (q == 17 && C0 == 0);
            float4 v = make_float4(0.f, 0.f, 0.f, 0.f);
            if ((unsigned)gr < 128u && cok)
                v = *(const float4*)(pp + (size_t)gr * 128 + C0 - 4 + 4 * q);
            *(float4*)&sx[r * 76 + 4 * q] = v;
        }
    }

    float w[25];
#pragma unroll
    for (int k = 0; k < 25; k++) w[k] = w1[1 * CC * 25 + c * 25 + k];
    const float bv = b1[1 * CC + c];
    __syncthreads();

    float acc[4][4];
    conv_core(sx, w, bv, tid, acc);

    const int tr = (tid >> 4) * 4, tc = (tid & 15) * 4;
    float* op = p2 + (size_t)plane * 16384 + (size_t)(R0 + tr) * 128 + C0 + tc;
#pragma unroll
    for (int i = 0; i < 4; i++)
        *(float4*)(op + (size_t)i * 128) = make_float4(acc[i][0], acc[i][1], acc[i][2], acc[i][3]);
}

// ---------------------------------------------------------------------------
// k_c3m: dwconv3 on p2 + 2x2 maxpool epilogue -> t2 (64^2/plane).
// ---------------------------------------------------------------------------
__global__ __launch_bounds__(256, 8) void k_c3m(
    const float* __restrict__ p2, const float* __restrict__ w1,
    const float* __restrict__ b1, float* __restrict__ t2)
{
    const int plane = blockIdx.z;
    const int c = plane & 63;
    const int C0 = blockIdx.x * 64, R0 = blockIdx.y * 64;
    const int tid = threadIdx.x;

    __shared__ __align__(16) float sx[68 * 76];
    const float* pp = p2 + (size_t)plane * 16384;

#pragma unroll
    for (int k = 0; k < 5; k++) {
        int i = tid + k * 256;
        if (i < 68 * 18) {
            int r = i / 18, q = i - r * 18;
            int gr = R0 - 2 + r;
            bool cok = (q >= 1 && q <= 16) || (q == 0 && C0 == 64) || (q == 17 && C0 == 0);
            float4 v = make_float4(0.f, 0.f, 0.f, 0.f);
            if ((unsigned)gr < 128u && cok)
                v = *(const float4*)(pp + (size_t)gr * 128 + C0 - 4 + 4 * q);
            *(float4*)&sx[r * 76 + 4 * q] = v;
        }
    }

    float w[25];
#pragma unroll
    for (int k = 0; k < 25; k++) w[k] = w1[2 * CC * 25 + c * 25 + k];
    const float bv = b1[2 * CC + c];
    __syncthreads();

    float acc[4][4];
    conv_core(sx, w, bv, tid, acc);

    const int tr = (tid >> 4) * 4, tc = (tid & 15) * 4;
    const int pr0 = (R0 + tr) >> 1, pc0 = (C0 + tc) >> 1;
#pragma unroll
    for (int ii = 0; ii < 2; ii++) {
        float m0 = fmaxf(fmaxf(acc[2 * ii][0], acc[2 * ii][1]),
                         fmaxf(acc[2 * ii + 1][0], acc[2 * ii + 1][1]));
        float m1 = fmaxf(fmaxf(acc[2 * ii][2], acc[2 * ii][3]),
                         fmaxf(acc[2 * ii + 1][2], acc[2 * ii + 1][3]));
        *(float2*)&t2[((size_t)plane * 64 + pr0 + ii) * 64 + pc0] = make_float2(m0, m1);
    }
}

// 2x4 e12 conv (Stage B): 6 rows x 3 float4; outputs at src+(2+i)*SS+4+j.
template<int SS>
__device__ __forceinline__ void conv2x4_e12(const float* __restrict__ src,
                                            const float* __restrict__ wr,
                                            float bv, float a[2][4])
{
#pragma unroll
    for (int i = 0; i < 2; i++)
#pragma unroll
        for (int j = 0; j < 4; j++) a[i][j] = bv;
#pragma unroll
    for (int ir = 0; ir < 6; ir++) {
        const float* s = src + ir * SS;
        float4 A = *(const float4*)s;
        float4 B = *(const float4*)(s + 4);
        float4 C = *(const float4*)(s + 8);
        float e[12] = {A.x, A.y, A.z, A.w, B.x, B.y, B.z, B.w, C.x, C.y, C.z, C.w};
#pragma unroll
        for (int i = 0; i < 2; i++) {
            const int ky = ir - i;
            if (ky >= 0 && ky < 5) {
#pragma unroll
                for (int kx = 0; kx < 5; kx++) {
                    const float wv = wr[ky * 5 + kx];
#pragma unroll
                    for (int j = 0; j < 4; j++) a[i][j] += e[2 + j + kx] * wv;
                }
            }
        }
    }
}

// ---------------------------------------------------------------------------
// Stage B: per-plane 3x dwconv(64^2) + mean on t2. LDS 68x72, in place,
// 512 threads, 2x4 tiles (exact). conv3 -> mean fused.
// ---------------------------------------------------------------------------
__global__ __launch_bounds__(512, 4) void k_b(
    const float* __restrict__ t2, const float* __restrict__ w2,
    const float* __restrict__ b2, float* __restrict__ g)
{
    const int plane = blockIdx.x;
    const int c = plane & 63;
    const int tid = threadIdx.x;

    __shared__ __align__(16) float sb[68 * 72];
    __shared__ float red[8];

    const float* tp = t2 + (size_t)plane * 4096;

#pragma unroll
    for (int k = 0; k < 3; k++) {
        int i = tid + k * 512;
        if (i < 68 * 18) {
            int r = i / 18, q = i % 18;
            float4 v = make_float4(0.f, 0.f, 0.f, 0.f);
            if (r >= 2 && r < 66 && q >= 1 && q <= 16)
                v = *(const float4*)(tp + (size_t)(r - 2) * 64 + 4 * (q - 1));
            *(float4*)&sb[r * 72 + 4 * q] = v;
        }
    }
    __syncthreads();

    const int v = tid >> 4, u = tid & 15;
    const float* rb = &sb[(2 * v) * 72 + 4 * u];
    float* wb = &sb[(2 * v + 2) * 72 + 4 * u + 4];

#pragma unroll
    for (int cv = 0; cv < 2; cv++) {
        float wr[25];
#pragma unroll
        for (int k = 0; k < 25; k++) wr[k] = w2[cv * CC * 25 + c * 25 + k];
        float a[2][4];
        conv2x4_e12<72>(rb, wr, b2[cv * CC + c], a);
        __syncthreads();
#pragma unroll
        for (int i = 0; i < 2; i++)
            *(float4*)(wb + i * 72) = make_float4(a[i][0], a[i][1], a[i][2], a[i][3]);
        __syncthreads();
    }

    float s;
    {
        float wr[25];
#pragma unroll
        for (int k = 0; k < 25; k++) wr[k] = w2[2 * CC * 25 + c * 25 + k];
        float a[2][4];
        conv2x4_e12<72>(rb, wr, b2[2 * CC + c], a);
        s = (a[0][0] + a[0][1] + a[0][2] + a[0][3]) +
            (a[1][0] + a[1][1] + a[1][2] + a[1][3]);
    }
#pragma unroll
    for (int off = 32; off > 0; off >>= 1) s += __shfl_down(s, off);
    if ((tid & 63) == 0) red[tid >> 6] = s;
    __syncthreads();
    if (tid == 0) {
        float t = 0.f;
#pragma unroll
        for (int k = 0; k < 8; k++) t += red[k];
        g[plane] = t * (1.f / 4096.f);
    }
}

// ---------------------------------------------------------------------------
__global__ __launch_bounds__(256) void k_kern(
    const float* __restrict__ g, const float* __restrict__ wk,
    const float* __restrict__ bk, float* __restrict__ kern)
{
    const int o = blockIdx.x * 256 + threadIdx.x;     // 0..12799
    const int b = o / 1600, oo = o - b * 1600;
    float v = bk[oo];
    const float* wp = wk + (size_t)oo * 64;
    const float* gp = g + b * 64;
#pragma unroll 16
    for (int k = 0; k < 64; k++) v += gp[k] * wp[k];
    kern[o] = v;
}

// ---------------------------------------------------------------------------
// Kernel 4: dynamic depthwise conv 5x5, 64x64 tile, 4x4 outputs/thread.
// ---------------------------------------------------------------------------
__global__ __launch_bounds__(256) void k_dyn(
    const float* __restrict__ x, const float* __restrict__ kern,
    const float* __restrict__ bias, float* __restrict__ out)
{
    const int plane = blockIdx.z;
    const int tx = blockIdx.x, ty = blockIdx.y;
    const int tid = threadIdx.x;

    __shared__ __align__(16) float sx[68 * 76];

    const float* xp = x + (size_t)plane * HH * WW;
    const int R0 = ty * 64, C0 = tx * 64;

#pragma unroll
    for (int k = 0; k < 5; k++) {
        int i = tid + k * 256;
        if (i < 68 * 18) {
            int r = i / 18, q = i - r * 18;
            int gr = R0 - 2 + r;
            int gc = C0 - 4 + 4 * q;
            float4 v = make_float4(0.f, 0.f, 0.f, 0.f);
            if ((unsigned)gr < HH && (unsigned)gc < WW)
                v = *(const float4*)(xp + (size_t)gr * WW + gc);
            *(float4*)&sx[r * 76 + 4 * q] = v;
        }
    }

    float w[25];
#pragma unroll
    for (int k = 0; k < 25; k++) w[k] = kern[(size_t)plane * 25 + k];
    const float bv = bias[plane & 63];

    __syncthreads();

    float acc[4][4];
    conv_core(sx, w, bv, tid, acc);

    const int tr = (tid >> 4) * 4, tc = (tid & 15) * 4;
    float* op = out + (size_t)plane * HH * WW + (size_t)(R0 + tr) * WW + C0 + tc;
#pragma unroll
    for (int i = 0; i < 4; i++)
        *(float4*)(op + (size_t)i * WW) = make_float4(acc[i][0], acc[i][1], acc[i][2], acc[i][3]);
}

// ---------------------------------------------------------------------------
extern "C" void kernel_launch(void* const* d_in, const int* in_sizes, int n_in,
                              void* d_out, int out_size, void* d_ws, size_t ws_size,
                              hipStream_t stream)
{
    const float* x    = (const float*)d_in[0];
    const float* w1   = (const float*)d_in[1];
    const float* b1   = (const float*)d_in[2];
    const float* w2   = (const float*)d_in[3];
    const float* b2   = (const float*)d_in[4];
    const float* wk   = (const float*)d_in[5];
    const float* bk   = (const float*)d_in[6];
    const float* bias = (const float*)d_in[7];
    float* out = (float*)d_out;

    float* ws   = (float*)d_ws;
    float* p1   = ws;                        // 512*128*128 = 8388608
    float* p2   = ws + 8388608;              // 8388608
    float* t2   = ws + 16777216;             // 512*64*64 = 2097152
    float* g    = ws + 18874368;             // 512
    float* kern = g + 512;                   // 12800

    k_c1 <<<dim3(2, 2, 512), 256, 0, stream>>>(x, w1, b1, p1);
    k_c2 <<<dim3(2, 2, 512), 256, 0, stream>>>(p1, w1, b1, p2);
    k_c3m<<<dim3(2, 2, 512), 256, 0, stream>>>(p2, w1, b1, t2);
    k_b  <<<dim3(512), 512, 0, stream>>>(t2, w2, b2, g);
    k_kern<<<dim3(50), 256, 0, stream>>>(g, wk, bk, kern);
    k_dyn<<<dim3(4, 4, 512), 256, 0, stream>>>(x, kern, bias, out);
}

// Round 12
// 114.944 us; speedup vs baseline: 1.2645x; 1.2645x over previous
//
#include <hip/hip_runtime.h>

#define CC 64
#define HH 256
#define WW 256
#define SROW 140   // stage-A LDS row stride (dwords); 140 % 32 = 12
#define BROW 76    // stage-B LDS row stride

// 4x4 e12 conv core: reads 8 rows x 3 aligned float4 at rb + ir*SS.
// e[m] <-> image col (cbase-4+m) where rb points at dword 4*cbase/... :
// outputs (i,j) at rows rbrow+2+i, cols cbase+j; tap = e[j+kx+2].
template<int SS>
__device__ __forceinline__ void conv4x4_e12(const float* __restrict__ rb,
                                            const float* __restrict__ w,
                                            float bv, float a[4][4])
{
#pragma unroll
    for (int i = 0; i < 4; i++)
#pragma unroll
        for (int j = 0; j < 4; j++) a[i][j] = bv;
#pragma unroll
    for (int ir = 0; ir < 8; ir++) {
        const float* s = rb + ir * SS;
        float4 A = *(const float4*)s;
        float4 B = *(const float4*)(s + 4);
        float4 C = *(const float4*)(s + 8);
        float e[12] = {A.x, A.y, A.z, A.w, B.x, B.y, B.z, B.w,
                       C.x, C.y, C.z, C.w};
#pragma unroll
        for (int i = 0; i < 4; i++) {
            const int ky = ir - i;
            if (ky >= 0 && ky < 5) {
#pragma unroll
                for (int kx = 0; kx < 5; kx++) {
                    const float wv = w[ky * 5 + kx];
#pragma unroll
                    for (int j = 0; j < 4; j++) a[i][j] += e[j + kx + 2] * wv;
                }
            }
        }
    }
}

// 1x4 e12 conv (stage B): 5 rows x 3 aligned float4.
__device__ __forceinline__ void conv1x4_e12B(const float* __restrict__ rb,
                                             const float* __restrict__ w,
                                             float bv, float a[4])
{
#pragma unroll
    for (int j = 0; j < 4; j++) a[j] = bv;
#pragma unroll
    for (int ir = 0; ir < 5; ir++) {
        const float* s = rb + ir * BROW;
        float4 A = *(const float4*)s;
        float4 B = *(const float4*)(s + 4);
        float4 C = *(const float4*)(s + 8);
        float e[12] = {A.x, A.y, A.z, A.w, B.x, B.y, B.z, B.w,
                       C.x, C.y, C.z, C.w};
#pragma unroll
        for (int kx = 0; kx < 5; kx++) {
            const float wv = w[ir * 5 + kx];
#pragma unroll
            for (int j = 0; j < 4; j++) a[j] += e[j + kx + 2] * wv;
        }
    }
}

// ---------------------------------------------------------------------------
// k_a: whole reduction chain per plane. 1024 thr, one block/plane, 2/CU.
// A-buffer: 132 rows x 140 dwords (73.9 KB). Row r = pooled row r-2;
// col j (0..127) at dword 8+j. Dwords 0..7 / 136..139 and rows 0,1,130,131
// are zeroed once in fill and NEVER written again -> free zero padding,
// full-coverage convs (no predicates), all reads/writes aligned b128.
// 3 A-convs in place (read+FMA -> bar -> write -> bar). conv3 feeds a
// register 2x2 maxpool written to the B-buffer (overlaid on dead sb[0..5168)).
// B: 68x76 e12 buffer, 1x4 strips (64x16 = 1024 exact), 2 convs in place,
// conv3 fused into the mean.
// ---------------------------------------------------------------------------
__global__ __launch_bounds__(1024, 8) void k_a(
    const float* __restrict__ x, const float* __restrict__ w1,
    const float* __restrict__ b1, const float* __restrict__ w2,
    const float* __restrict__ b2, float* __restrict__ g)
{
    const int plane = blockIdx.x;          // b*64 + c
    const int c = plane & 63;
    const int tid = threadIdx.x;

    __shared__ __align__(16) float sb[132 * SROW];
    __shared__ float red[16];
    float* Bb = sb;                        // B-buffer overlay, 68*76 dwords

    const float* xp = x + (size_t)plane * HH * WW;

    // ---- fill: avgpool(2x2) of x -> interior; margins zero. 132x35 f4. ----
#pragma unroll
    for (int k = 0; k < 5; k++) {
        int i = tid + k * 1024;
        if (i < 132 * 35) {
            int r = i / 35, f = i % 35;
            int d = 4 * f;
            float4 v = make_float4(0.f, 0.f, 0.f, 0.f);
            int p = r - 2;                 // pooled row
            if (d >= 8 && d < 136 && (unsigned)p < 128u) {
                int xc = 2 * (d - 8);      // x col, 32B aligned
                const float* p0 = xp + (size_t)(2 * p) * WW + xc;
                const float* p1 = p0 + WW;
                float4 a0 = *(const float4*)p0;
                float4 a1 = *(const float4*)(p0 + 4);
                float4 b0 = *(const float4*)p1;
                float4 b1v = *(const float4*)(p1 + 4);
                v.x = 0.25f * (a0.x + a0.y + b0.x + b0.y);
                v.y = 0.25f * (a0.z + a0.w + b0.z + b0.w);
                v.z = 0.25f * (a1.x + a1.y + b1v.x + b1v.y);
                v.w = 0.25f * (a1.z + a1.w + b1v.z + b1v.w);
            }
            *(float4*)&sb[r * SROW + d] = v;
        }
    }
    __syncthreads();

    // ---- stage A: 3 convs at 128^2, in place, 4x4 tile/thread (exact) ----
    const int v = tid >> 5, u = tid & 31;              // 32x32 tiles
    const float* rbA = &sb[(4 * v) * SROW + 4 * u + 4]; // e12 read base
    float* wbA = &sb[(4 * v + 2) * SROW + 8 + 4 * u];   // aligned write base

#pragma unroll
    for (int cv = 0; cv < 2; cv++) {
        float w[25];
#pragma unroll
        for (int k = 0; k < 25; k++) w[k] = w1[cv * CC * 25 + c * 25 + k]; // SGPR
        const float bv = b1[cv * CC + c];
        float a[4][4];
        conv4x4_e12<SROW>(rbA, w, bv, a);
        __syncthreads();
#pragma unroll
        for (int i = 0; i < 4; i++)
            *(float4*)(wbA + i * SROW) = make_float4(a[i][0], a[i][1], a[i][2], a[i][3]);
        __syncthreads();
    }

    // ---- conv3 + 2x2 maxpool -> B-buffer (overlay); margins zeroed here ----
    {
        float w[25];
#pragma unroll
        for (int k = 0; k < 25; k++) w[k] = w1[2 * CC * 25 + c * 25 + k];
        const float bv = b1[2 * CC + c];
        float a[4][4];
        conv4x4_e12<SROW>(rbA, w, bv, a);
        __syncthreads();                    // all A-reads done; sb dead
        // pooled 2x2 block of this tile -> B rows 2v+2,2v+3, dword 8+2u
#pragma unroll
        for (int ii = 0; ii < 2; ii++) {
            float m0 = fmaxf(fmaxf(a[2 * ii][0], a[2 * ii][1]),
                             fmaxf(a[2 * ii + 1][0], a[2 * ii + 1][1]));
            float m1 = fmaxf(fmaxf(a[2 * ii][2], a[2 * ii][3]),
                             fmaxf(a[2 * ii + 1][2], a[2 * ii + 1][3]));
            *(float2*)&Bb[(2 * v + 2 + ii) * BROW + 8 + 2 * u] = make_float2(m0, m1);
        }
        // zero B margins: rows 0,1,66,67 full (304) + rows 2..65 cols
        // d in {0..7, 72..75} (64*12 = 768) -> 1072 dwords
        for (int i = tid; i < 1072; i += 1024) {
            int idx;
            if (i < 304) {
                int rr = i / BROW;
                int rowz = (rr < 2) ? rr : 64 + rr;
                idx = rowz * BROW + (i % BROW);
            } else {
                int j = i - 304;
                int row = 2 + j / 12, k2 = j % 12;
                int col = (k2 < 8) ? k2 : 64 + k2;
                idx = row * BROW + col;
            }
            Bb[idx] = 0.f;
        }
    }
    __syncthreads();

    // ---- stage B: 64^2, 1x4 strips (64 rows x 16 strips = 1024 exact) ----
    const int q = tid >> 4, u2 = tid & 15;
    const float* rbB = &Bb[q * BROW + 4 * u2 + 4];
    float* wbB = &Bb[(q + 2) * BROW + 8 + 4 * u2];

#pragma unroll
    for (int cv = 0; cv < 2; cv++) {
        float w[25];
#pragma unroll
        for (int k = 0; k < 25; k++) w[k] = w2[cv * CC * 25 + c * 25 + k];
        float a[4];
        conv1x4_e12B(rbB, w, b2[cv * CC + c], a);
        __syncthreads();
        *(float4*)wbB = make_float4(a[0], a[1], a[2], a[3]);
        __syncthreads();
    }

    // ---- B conv3 -> mean (never stored) ----
    float s;
    {
        float w[25];
#pragma unroll
        for (int k = 0; k < 25; k++) w[k] = w2[2 * CC * 25 + c * 25 + k];
        float a[4];
        conv1x4_e12B(rbB, w, b2[2 * CC + c], a);
        s = a[0] + a[1] + a[2] + a[3];
    }
#pragma unroll
    for (int off = 32; off > 0; off >>= 1) s += __shfl_down(s, off);
    if ((tid & 63) == 0) red[tid >> 6] = s;
    __syncthreads();
    if (tid == 0) {
        float t = 0.f;
#pragma unroll
        for (int k = 0; k < 16; k++) t += red[k];
        g[plane] = t * (1.f / 4096.f);
    }
}

// ---------------------------------------------------------------------------
// k_kern: kern[o] = dot(g[b,:], wk[oo,:]) + bk[oo]
// ---------------------------------------------------------------------------
__global__ __launch_bounds__(256) void k_kern(
    const float* __restrict__ g, const float* __restrict__ wk,
    const float* __restrict__ bk, float* __restrict__ kern)
{
    const int o = blockIdx.x * 256 + threadIdx.x;     // 0..12799
    const int b = o / 1600, oo = o - b * 1600;
    float v = bk[oo];
    const float* wp = wk + (size_t)oo * 64;
    const float* gp = g + b * 64;
#pragma unroll 16
    for (int k = 0; k < 64; k++) v += gp[k] * wp[k];
    kern[o] = v;
}

// ---------------------------------------------------------------------------
// k_dyn: dynamic depthwise conv 5x5, 64x64 tile, 4x4 outputs/thread.
// ---------------------------------------------------------------------------
__global__ __launch_bounds__(256) void k_dyn(
    const float* __restrict__ x, const float* __restrict__ kern,
    const float* __restrict__ bias, float* __restrict__ out)
{
    const int plane = blockIdx.z;
    const int tx = blockIdx.x, ty = blockIdx.y;
    const int tid = threadIdx.x;

    __shared__ __align__(16) float sx[68 * 76];

    const float* xp = x + (size_t)plane * HH * WW;
    const int R0 = ty * 64, C0 = tx * 64;

#pragma unroll
    for (int k = 0; k < 5; k++) {
        int i = tid + k * 256;
        if (i < 68 * 18) {
            int r = i / 18, q = i - r * 18;
            int gr = R0 - 2 + r;
            int gc = C0 - 4 + 4 * q;
            float4 v = make_float4(0.f, 0.f, 0.f, 0.f);
            if ((unsigned)gr < HH && (unsigned)gc < WW)
                v = *(const float4*)(xp + (size_t)gr * WW + gc);
            *(float4*)&sx[r * 76 + 4 * q] = v;
        }
    }

    float w[25];
#pragma unroll
    for (int k = 0; k < 25; k++) w[k] = kern[(size_t)plane * 25 + k];   // uniform
    const float bv = bias[plane & 63];

    __syncthreads();

    const int tr = (tid >> 4) * 4, tc = (tid & 15) * 4;
    float acc[4][4];
    conv4x4_e12<76>(&sx[tr * 76 + tc], w, bv, acc);

    float* op = out + (size_t)plane * HH * WW + (size_t)(R0 + tr) * WW + C0 + tc;
#pragma unroll
    for (int i = 0; i < 4; i++)
        *(float4*)(op + (size_t)i * WW) = make_float4(acc[i][0], acc[i][1], acc[i][2], acc[i][3]);
}

// ---------------------------------------------------------------------------
extern "C" void kernel_launch(void* const* d_in, const int* in_sizes, int n_in,
                              void* d_out, int out_size, void* d_ws, size_t ws_size,
                              hipStream_t stream)
{
    const float* x    = (const float*)d_in[0];
    const float* w1   = (const float*)d_in[1];
    const float* b1   = (const float*)d_in[2];
    const float* w2   = (const float*)d_in[3];
    const float* b2   = (const float*)d_in[4];
    const float* wk   = (const float*)d_in[5];
    const float* bk   = (const float*)d_in[6];
    const float* bias = (const float*)d_in[7];
    float* out = (float*)d_out;

    float* ws   = (float*)d_ws;
    float* g    = ws;                       // 512
    float* kern = ws + 512;                 // 12800

    k_a<<<dim3(512), 1024, 0, stream>>>(x, w1, b1, w2, b2, g);
    k_kern<<<dim3(50), 256, 0, stream>>>(g, wk, bk, kern);
    k_dyn<<<dim3(4, 4, 512), 256, 0, stream>>>(x, kern, bias, out);
}

// Round 13
// 114.670 us; speedup vs baseline: 1.2676x; 1.0024x over previous
//
#include <hip/hip_runtime.h>

#define CC 64
#define HH 256
#define WW 256
#define SROW 140   // stage-A LDS row stride (dwords)
#define BROW 76    // k_keff LDS row stride

// 4x4 e12 conv core: reads 8 rows x 3 aligned float4 at rb + ir*SS.
template<int SS>
__device__ __forceinline__ void conv4x4_e12(const float* __restrict__ rb,
                                            const float* __restrict__ w,
                                            float bv, float a[4][4])
{
#pragma unroll
    for (int i = 0; i < 4; i++)
#pragma unroll
        for (int j = 0; j < 4; j++) a[i][j] = bv;
#pragma unroll
    for (int ir = 0; ir < 8; ir++) {
        const float* s = rb + ir * SS;
        float4 A = *(const float4*)s;
        float4 B = *(const float4*)(s + 4);
        float4 C = *(const float4*)(s + 8);
        float e[12] = {A.x, A.y, A.z, A.w, B.x, B.y, B.z, B.w,
                       C.x, C.y, C.z, C.w};
#pragma unroll
        for (int i = 0; i < 4; i++) {
            const int ky = ir - i;
            if (ky >= 0 && ky < 5) {
#pragma unroll
                for (int kx = 0; kx < 5; kx++) {
                    const float wv = w[ky * 5 + kx];
#pragma unroll
                    for (int j = 0; j < 4; j++) a[i][j] += e[j + kx + 2] * wv;
                }
            }
        }
    }
}

// 1x4 e12 conv at stride BROW: 5 rows x 3 aligned float4.
__device__ __forceinline__ void conv1x4_e12B(const float* __restrict__ rb,
                                             const float* __restrict__ w,
                                             float bv, float a[4])
{
#pragma unroll
    for (int j = 0; j < 4; j++) a[j] = bv;
#pragma unroll
    for (int ir = 0; ir < 5; ir++) {
        const float* s = rb + ir * BROW;
        float4 A = *(const float4*)s;
        float4 B = *(const float4*)(s + 4);
        float4 C = *(const float4*)(s + 8);
        float e[12] = {A.x, A.y, A.z, A.w, B.x, B.y, B.z, B.w,
                       C.x, C.y, C.z, C.w};
#pragma unroll
        for (int kx = 0; kx < 5; kx++) {
            const float wv = w[ir * 5 + kx];
#pragma unroll
            for (int j = 0; j < 4; j++) a[j] += e[j + kx + 2] * wv;
        }
    }
}

// ---------------------------------------------------------------------------
// k_keff: per channel c, linearize stage B. g = <K_eff, t2> + beta where
// K_eff = W1^T W2^T W3^T 1 / 4096 (flipped-kernel zero-padded conv chain on a
// ones image; Wi = stage-B conv i) and
// beta = (b2[0]*sum(u2) + b2[1]*sum(u1) + 4096*b2[2]) / 4096.
// kq layout: kq[c][v][u][4] = {K[2v][2u],K[2v][2u+1],K[2v+1][2u],K[2v+1][2u+1]}/4096
// matching k_a's conv3 tile (v,u) register maxpool.
// ---------------------------------------------------------------------------
__global__ __launch_bounds__(512, 4) void k_keff(
    const float* __restrict__ w2, const float* __restrict__ b2,
    float* __restrict__ kq, float* __restrict__ beta)
{
    const int c = blockIdx.x;           // 0..63
    const int tid = threadIdx.x;
    __shared__ __align__(16) float sb[68 * BROW];
    __shared__ float red[16];

    // init: ones interior (rows 2..65, dwords 8..71), zero margins
    for (int i = tid; i < 68 * 19; i += 512) {
        int r = i / 19, q = i % 19;
        int d = 4 * q;
        float4 v = make_float4(0.f, 0.f, 0.f, 0.f);
        if (r >= 2 && r < 66 && d >= 8 && d < 72)
            v = make_float4(1.f, 1.f, 1.f, 1.f);
        *(float4*)&sb[r * BROW + d] = v;
    }
    __syncthreads();

    const int r0 = tid >> 4;            // 0..31 (strips r0 and r0+32)
    const int u = tid & 15;
    float S0 = 0.f, S1 = 0.f;           // sum(u1), sum(u2)

#pragma unroll
    for (int step = 0; step < 2; step++) {
        const int cv = 2 - step;        // w2[2] then w2[1], flipped
        float w[25];
#pragma unroll
        for (int k = 0; k < 25; k++) w[k] = w2[cv * CC * 25 + c * 25 + (24 - k)];
        float a0[4], a1[4];
        conv1x4_e12B(&sb[r0 * BROW + 4 * u + 4], w, 0.f, a0);
        conv1x4_e12B(&sb[(r0 + 32) * BROW + 4 * u + 4], w, 0.f, a1);
        __syncthreads();
        *(float4*)&sb[(r0 + 2) * BROW + 8 + 4 * u] = make_float4(a0[0], a0[1], a0[2], a0[3]);
        *(float4*)&sb[(r0 + 34) * BROW + 8 + 4 * u] = make_float4(a1[0], a1[1], a1[2], a1[3]);
        float s = a0[0] + a0[1] + a0[2] + a0[3] + a1[0] + a1[1] + a1[2] + a1[3];
        if (step == 0) S0 += s; else S1 += s;
        __syncthreads();
    }

    // final conv with flipped w2[0] -> K, back into sb
    {
        float w[25];
#pragma unroll
        for (int k = 0; k < 25; k++) w[k] = w2[0 * CC * 25 + c * 25 + (24 - k)];
        float a0[4], a1[4];
        conv1x4_e12B(&sb[r0 * BROW + 4 * u + 4], w, 0.f, a0);
        conv1x4_e12B(&sb[(r0 + 32) * BROW + 4 * u + 4], w, 0.f, a1);
        __syncthreads();
        *(float4*)&sb[(r0 + 2) * BROW + 8 + 4 * u] = make_float4(a0[0], a0[1], a0[2], a0[3]);
        *(float4*)&sb[(r0 + 34) * BROW + 8 + 4 * u] = make_float4(a1[0], a1[1], a1[2], a1[3]);
        __syncthreads();
    }

    // regroup into kq (2x2 per entry), scaled 1/4096
    for (int i = tid; i < 1024; i += 512) {
        int v = i >> 5, uu = i & 31;
        float k00 = sb[(2 * v + 2) * BROW + 8 + 2 * uu];
        float k01 = sb[(2 * v + 2) * BROW + 8 + 2 * uu + 1];
        float k10 = sb[(2 * v + 3) * BROW + 8 + 2 * uu];
        float k11 = sb[(2 * v + 3) * BROW + 8 + 2 * uu + 1];
        *(float4*)&kq[((size_t)(c * 32 + v) * 32 + uu) * 4] =
            make_float4(k00 * (1.f / 4096.f), k01 * (1.f / 4096.f),
                        k10 * (1.f / 4096.f), k11 * (1.f / 4096.f));
    }

    // reduce S0,S1 -> beta
#pragma unroll
    for (int off = 32; off > 0; off >>= 1) {
        S0 += __shfl_down(S0, off);
        S1 += __shfl_down(S1, off);
    }
    if ((tid & 63) == 0) { red[tid >> 6] = S0; red[8 + (tid >> 6)] = S1; }
    __syncthreads();
    if (tid == 0) {
        float t0 = 0.f, t1 = 0.f;
#pragma unroll
        for (int k = 0; k < 8; k++) { t0 += red[k]; t1 += red[8 + k]; }
        beta[c] = (b2[0 * CC + c] * t1 + b2[1 * CC + c] * t0 +
                   4096.f * b2[2 * CC + c]) * (1.f / 4096.f);
    }
}

// ---------------------------------------------------------------------------
// k_a: avgpool + conv1 + conv2 + conv3 + reg-maxpool + <.,kq> dot -> g.
// 1024 thr, one block/plane, 2 blocks/CU. A-buffer 132x140 as R12 (verified).
// Only 6 barriers: fill,1 | c1 read->w,2 | c2 read->w,2 | reduce,1.
// ---------------------------------------------------------------------------
__global__ __launch_bounds__(1024, 8) void k_a(
    const float* __restrict__ x, const float* __restrict__ w1,
    const float* __restrict__ b1, const float* __restrict__ kq,
    const float* __restrict__ beta, float* __restrict__ g)
{
    const int plane = blockIdx.x;          // b*64 + c
    const int c = plane & 63;
    const int tid = threadIdx.x;

    __shared__ __align__(16) float sb[132 * SROW];
    __shared__ float red[16];

    const float* xp = x + (size_t)plane * HH * WW;

    // fill: avgpool(2x2) of x -> interior; margins zero. 132x35 f4.
#pragma unroll
    for (int k = 0; k < 5; k++) {
        int i = tid + k * 1024;
        if (i < 132 * 35) {
            int r = i / 35, f = i % 35;
            int d = 4 * f;
            float4 v = make_float4(0.f, 0.f, 0.f, 0.f);
            int p = r - 2;                 // pooled row
            if (d >= 8 && d < 136 && (unsigned)p < 128u) {
                int xc = 2 * (d - 8);
                const float* p0 = xp + (size_t)(2 * p) * WW + xc;
                const float* p1 = p0 + WW;
                float4 a0 = *(const float4*)p0;
                float4 a1 = *(const float4*)(p0 + 4);
                float4 b0 = *(const float4*)p1;
                float4 b1v = *(const float4*)(p1 + 4);
                v.x = 0.25f * (a0.x + a0.y + b0.x + b0.y);
                v.y = 0.25f * (a0.z + a0.w + b0.z + b0.w);
                v.z = 0.25f * (a1.x + a1.y + b1v.x + b1v.y);
                v.w = 0.25f * (a1.z + a1.w + b1v.z + b1v.w);
            }
            *(float4*)&sb[r * SROW + d] = v;
        }
    }
    __syncthreads();

    const int v = tid >> 5, u = tid & 31;              // 32x32 tiles
    const float* rbA = &sb[(4 * v) * SROW + 4 * u + 4];
    float* wbA = &sb[(4 * v + 2) * SROW + 8 + 4 * u];

    // conv1, conv2 in place
#pragma unroll
    for (int cv = 0; cv < 2; cv++) {
        float w[25];
#pragma unroll
        for (int k = 0; k < 25; k++) w[k] = w1[cv * CC * 25 + c * 25 + k]; // SGPR
        const float bv = b1[cv * CC + c];
        float a[4][4];
        conv4x4_e12<SROW>(rbA, w, bv, a);
        __syncthreads();
#pragma unroll
        for (int i = 0; i < 4; i++)
            *(float4*)(wbA + i * SROW) = make_float4(a[i][0], a[i][1], a[i][2], a[i][3]);
        __syncthreads();
    }

    // conv3 + register 2x2 maxpool + dot with kq
    float partial;
    {
        float w[25];
#pragma unroll
        for (int k = 0; k < 25; k++) w[k] = w1[2 * CC * 25 + c * 25 + k];
        const float bv = b1[2 * CC + c];
        float a[4][4];
        conv4x4_e12<SROW>(rbA, w, bv, a);
        float m00 = fmaxf(fmaxf(a[0][0], a[0][1]), fmaxf(a[1][0], a[1][1]));
        float m01 = fmaxf(fmaxf(a[0][2], a[0][3]), fmaxf(a[1][2], a[1][3]));
        float m10 = fmaxf(fmaxf(a[2][0], a[2][1]), fmaxf(a[3][0], a[3][1]));
        float m11 = fmaxf(fmaxf(a[2][2], a[2][3]), fmaxf(a[3][2], a[3][3]));
        float4 kk = *(const float4*)&kq[((size_t)(c * 32 + v) * 32 + u) * 4];
        partial = m00 * kk.x + m01 * kk.y + m10 * kk.z + m11 * kk.w;
    }
#pragma unroll
    for (int off = 32; off > 0; off >>= 1) partial += __shfl_down(partial, off);
    if ((tid & 63) == 0) red[tid >> 6] = partial;
    __syncthreads();
    if (tid == 0) {
        float t = 0.f;
#pragma unroll
        for (int k = 0; k < 16; k++) t += red[k];
        g[plane] = t + beta[c];
    }
}

// ---------------------------------------------------------------------------
// k_kern: kern[o] = dot(g[b,:], wk[oo,:]) + bk[oo]
// ---------------------------------------------------------------------------
__global__ __launch_bounds__(256) void k_kern(
    const float* __restrict__ g, const float* __restrict__ wk,
    const float* __restrict__ bk, float* __restrict__ kern)
{
    const int o = blockIdx.x * 256 + threadIdx.x;     // 0..12799
    const int b = o / 1600, oo = o - b * 1600;
    float v = bk[oo];
    const float* wp = wk + (size_t)oo * 64;
    const float* gp = g + b * 64;
#pragma unroll 16
    for (int k = 0; k < 64; k++) v += gp[k] * wp[k];
    kern[o] = v;
}

// ---------------------------------------------------------------------------
// k_dyn: dynamic depthwise conv 5x5, 64x64 tile, 4x4 outputs/thread.
// ---------------------------------------------------------------------------
__global__ __launch_bounds__(256) void k_dyn(
    const float* __restrict__ x, const float* __restrict__ kern,
    const float* __restrict__ bias, float* __restrict__ out)
{
    const int plane = blockIdx.z;
    const int tx = blockIdx.x, ty = blockIdx.y;
    const int tid = threadIdx.x;

    __shared__ __align__(16) float sx[68 * 76];

    const float* xp = x + (size_t)plane * HH * WW;
    const int R0 = ty * 64, C0 = tx * 64;

#pragma unroll
    for (int k = 0; k < 5; k++) {
        int i = tid + k * 256;
        if (i < 68 * 18) {
            int r = i / 18, q = i - r * 18;
            int gr = R0 - 2 + r;
            int gc = C0 - 4 + 4 * q;
            float4 v = make_float4(0.f, 0.f, 0.f, 0.f);
            if ((unsigned)gr < HH && (unsigned)gc < WW)
                v = *(const float4*)(xp + (size_t)gr * WW + gc);
            *(float4*)&sx[r * 76 + 4 * q] = v;
        }
    }

    float w[25];
#pragma unroll
    for (int k = 0; k < 25; k++) w[k] = kern[(size_t)plane * 25 + k];   // uniform
    const float bv = bias[plane & 63];

    __syncthreads();

    const int tr = (tid >> 4) * 4, tc = (tid & 15) * 4;
    float acc[4][4];
    conv4x4_e12<76>(&sx[tr * 76 + tc], w, bv, acc);

    float* op = out + (size_t)plane * HH * WW + (size_t)(R0 + tr) * WW + C0 + tc;
#pragma unroll
    for (int i = 0; i < 4; i++)
        *(float4*)(op + (size_t)i * WW) = make_float4(acc[i][0], acc[i][1], acc[i][2], acc[i][3]);
}

// ---------------------------------------------------------------------------
extern "C" void kernel_launch(void* const* d_in, const int* in_sizes, int n_in,
                              void* d_out, int out_size, void* d_ws, size_t ws_size,
                              hipStream_t stream)
{
    const float* x    = (const float*)d_in[0];
    const float* w1   = (const float*)d_in[1];
    const float* b1   = (const float*)d_in[2];
    const float* w2   = (const float*)d_in[3];
    const float* b2   = (const float*)d_in[4];
    const float* wk   = (const float*)d_in[5];
    const float* bk   = (const float*)d_in[6];
    const float* bias = (const float*)d_in[7];
    float* out = (float*)d_out;

    float* ws   = (float*)d_ws;
    float* kq   = ws;                       // 64*32*32*4 = 262144 floats
    float* beta = ws + 262144;              // 64
    float* g    = ws + 262208;              // 512
    float* kern = ws + 262720;              // 12800

    k_keff<<<dim3(64), 512, 0, stream>>>(w2, b2, kq, beta);
    k_a<<<dim3(512), 1024, 0, stream>>>(x, w1, b1, kq, beta, g);
    k_kern<<<dim3(50), 256, 0, stream>>>(g, wk, bk, kern);
    k_dyn<<<dim3(4, 4, 512), 256, 0, stream>>>(x, kern, bias, out);
}